// Round 1
// baseline (833.301 us; speedup 1.0000x reference)
//
#include <hip/hip_runtime.h>
#include <math.h>

// ---- problem constants ----
constexpr int B  = 32;
constexpr int N  = 196;   // tokens
constexpr int D  = 768;   // channels
constexpr int E  = 200;   // experts
constexpr int TK = 20;    // top-k
constexpr int H  = 196;   // hidden (N * hidden_ratio)

constexpr int NP = 224;   // padded K-dim (196 -> 7*32) for both GEMMs
constexpr int HR = 208;   // padded output-col rows stored for W1b/W2b (196 -> 13*16)
constexpr int WROWS = 224;// staged W rows in LDS (208 data + 16 zero)

constexpr int LZ = 232;   // LDS stride for z / a tiles (bf16 elems, 16B-aligned rows)
constexpr int LW = 40;    // LDS stride for W tiles (bf16 elems, 80B rows)

typedef __bf16 bf16x8 __attribute__((ext_vector_type(8)));
typedef float  f32x4  __attribute__((ext_vector_type(4)));

__device__ __forceinline__ float gelu_tanh(float x) {
  float x3 = x * x * x;
  float u = 0.7978845608028654f * (x + 0.044715f * x3);
  return 0.5f * x * (1.0f + tanhf(u));
}

// ---------------------------------------------------------------------------
// Kernel 1: fused token-mean + layernorm-over-N, write z bf16 (B,D,224) padded
// thread t -> (b,d); reads of x[b,n,d] are coalesced across consecutive d.
// ---------------------------------------------------------------------------
__global__ void k_ln(const float* __restrict__ x, __bf16* __restrict__ zb,
                     float* __restrict__ mu) {
  int t = blockIdx.x * 256 + threadIdx.x;        // [0, B*D)
  if (t >= B * D) return;
  int b = t / D;
  const float* xp = x + (size_t)b * N * D + (t % D);
  float s = 0.f, sq = 0.f;
  #pragma unroll 4
  for (int n = 0; n < N; ++n) {
    float v = xp[(size_t)n * D];
    s += v; sq += v * v;
  }
  float m   = s * (1.0f / N);
  float var = sq * (1.0f / N) - m * m;
  float rs  = rsqrtf(var + 1e-5f);
  mu[t] = m;
  __bf16* zr = zb + (size_t)t * NP;
  #pragma unroll 4
  for (int n = 0; n < N; ++n) {
    float v = xp[(size_t)n * D];
    zr[n] = (__bf16)((v - m) * rs);
  }
  for (int n = N; n < NP; ++n) zr[n] = (__bf16)0.f;
}

// ---------------------------------------------------------------------------
// Kernel 2: convert W1,W2 -> zero-padded bf16 (E,208,224); Wo -> bf16 (768,768)
// ---------------------------------------------------------------------------
__global__ void k_convert(const float* __restrict__ W1, const float* __restrict__ W2,
                          const float* __restrict__ Wo,
                          __bf16* __restrict__ W1b, __bf16* __restrict__ W2b,
                          __bf16* __restrict__ Wob) {
  size_t i = (size_t)blockIdx.x * 256 + threadIdx.x;
  const size_t WN = (size_t)E * HR * NP;          // 9,318,400
  if (i < WN) {
    int e = (int)(i / (HR * NP));
    int rem = (int)(i % (HR * NP));
    int r = rem / NP, c = rem % NP;
    float v = (r < H && c < N) ? W1[((size_t)e * H + r) * N + c] : 0.f;
    W1b[i] = (__bf16)v;
  } else if (i < 2 * WN) {
    size_t j = i - WN;
    int e = (int)(j / (HR * NP));
    int rem = (int)(j % (HR * NP));
    int r = rem / NP, c = rem % NP;
    float v = (r < N && c < H) ? W2[((size_t)e * N + r) * H + c] : 0.f;
    W2b[j] = (__bf16)v;
  } else {
    size_t j = i - 2 * WN;
    if (j < (size_t)D * D) Wob[j] = (__bf16)Wo[j];
  }
}

// ---------------------------------------------------------------------------
// Kernel 3: router — logits, softmax, top-20 (desc, low-index tie-break),
// renormalized weights. One block per sample b.
// ---------------------------------------------------------------------------
__global__ void k_router(const float* __restrict__ mu, const float* __restrict__ Wr,
                         float* __restrict__ probs, int* __restrict__ idxg,
                         float* __restrict__ wg) {
  int b = blockIdx.x;
  int t = threadIdx.x;
  __shared__ float sp[E];
  __shared__ float smax, ssum;
  __shared__ float svals[TK];
  __shared__ int   sidx[TK];

  float logit = 0.f;
  if (t < E) {
    const float* m  = mu + (size_t)b * D;
    const float* wr = Wr + (size_t)t * D;
    float acc = 0.f;
    #pragma unroll 4
    for (int d = 0; d < D; ++d) acc = fmaf(m[d], wr[d], acc);
    logit = acc;
    sp[t] = acc;
  }
  __syncthreads();
  if (t == 0) {
    float mx = sp[0];
    for (int e = 1; e < E; ++e) mx = fmaxf(mx, sp[e]);
    smax = mx;
  }
  __syncthreads();
  if (t < E) sp[t] = expf(logit - smax);
  __syncthreads();
  if (t == 0) {
    float s = 0.f;
    for (int e = 0; e < E; ++e) s += sp[e];
    ssum = s;
  }
  __syncthreads();
  if (t < E) {
    sp[t] = sp[t] / ssum;
    probs[(size_t)b * E + t] = sp[t];
  }
  __syncthreads();

  // iterative top-k on wave 0
  for (int k = 0; k < TK; ++k) {
    if (t < 64) {
      float bv = -1e30f; int bi = 0;
      for (int e = t; e < E; e += 64) {
        float v = sp[e];
        if (v > bv) { bv = v; bi = e; }
      }
      #pragma unroll
      for (int off = 32; off > 0; off >>= 1) {
        float ov = __shfl_down(bv, off);
        int   oi = __shfl_down(bi, off);
        if (ov > bv || (ov == bv && oi < bi)) { bv = ov; bi = oi; }
      }
      if (t == 0) {
        svals[k] = bv; sidx[k] = bi;
        sp[bi] = -2e30f;
      }
    }
    __syncthreads();
  }
  if (t == 0) {
    float s = 0.f;
    for (int k = 0; k < TK; ++k) s += svals[k];
    float inv = 1.0f / s;
    for (int k = 0; k < TK; ++k) {
      wg[b * TK + k]   = svals[k] * inv;
      idxg[b * TK + k] = sidx[k];
    }
  }
}

// ---------------------------------------------------------------------------
// Kernel 4: aux loss -> out[B*N*D]
// ---------------------------------------------------------------------------
__global__ void k_aux(const float* __restrict__ probs, const int* __restrict__ idxg,
                      float* __restrict__ out_aux) {
  __shared__ float cs[E];
  int t = threadIdx.x;
  if (t < E) {
    float s = 0.f;
    for (int b = 0; b < B; ++b) s += probs[(size_t)b * E + t];
    cs[t] = s;
  }
  __syncthreads();
  if (t == 0) {
    float a = 0.f;
    for (int b = 0; b < B; ++b) a += cs[idxg[b * TK]];
    out_aux[0] = a * ((float)E / ((float)B * (float)B));
  }
}

// ---------------------------------------------------------------------------
// Kernel 5: fused expert MLP. Block = (b, d-tile of 64, k-half of 10 experts).
// GEMM1: h = z @ W1^T; a = gelu(h + b1) * w_k -> LDS;
// GEMM2: mix-acc += a @ W2^T (accumulates across the 10 experts in registers).
// 16x16x32 bf16 MFMA; per-wave job 32 rows x 112 cols (2x7 tiles).
// ---------------------------------------------------------------------------
__global__ __launch_bounds__(256, 2) void k_expert(
    const __bf16* __restrict__ zb, const __bf16* __restrict__ W1b,
    const __bf16* __restrict__ W2b, const float* __restrict__ b1,
    const float* __restrict__ b2, const int* __restrict__ idxg,
    const float* __restrict__ wg, float* __restrict__ mixp) {
  __shared__ __bf16 zs[64 * LZ];
  __shared__ __bf16 at[64 * LZ];
  __shared__ __bf16 wsT[WROWS * LW];

  int bi = blockIdx.x;
  int kh = bi & 1;
  int dt = (bi >> 1) % 12;
  int b  = bi / 24;
  int d0 = dt * 64;
  int t = threadIdx.x;
  int lane = t & 63, wave = t >> 6;
  int quad = lane >> 4, l16 = lane & 15;
  int wrow = (wave & 1) * 32;
  int wcol = (wave >> 1) * 112;

  // stage z tile: zb rows are contiguous -> flat 16B copies
  {
    const uint4* src = (const uint4*)(zb + ((size_t)b * D + d0) * NP);
    for (int p = t; p < 1792; p += 256) {
      int row = p / 28, sub = p % 28;
      uint4 v = src[p];
      *(uint4*)&zs[row * LZ + sub * 8] = v;
    }
  }
  // zero the 16 extra staged W rows (208..223) once
  for (int p = t; p < 16 * LW; p += 256) wsT[HR * LW + p] = (__bf16)0.f;
  __syncthreads();

  f32x4 macc[14];
  #pragma unroll
  for (int i = 0; i < 14; ++i) macc[i] = (f32x4){0.f, 0.f, 0.f, 0.f};

  #pragma unroll 1
  for (int kk = kh * 10; kk < kh * 10 + 10; ++kk) {
    int   e   = idxg[b * TK + kk];
    float wkv = wg[b * TK + kk];

    // ---- GEMM1: h = z @ W1^T ----
    f32x4 hacc[14];
    #pragma unroll
    for (int i = 0; i < 14; ++i) hacc[i] = (f32x4){0.f, 0.f, 0.f, 0.f};

    const uint4* w1src = (const uint4*)(W1b + (size_t)e * HR * NP);
    #pragma unroll 1
    for (int c = 0; c < 7; ++c) {
      int k0 = c * 32;
      __syncthreads();                       // protect wsT from prior readers
      for (int p = t; p < 832; p += 256) {
        int r = p >> 2, sub = p & 3;
        uint4 v = w1src[r * 28 + (k0 >> 3) + sub];
        *(uint4*)&wsT[r * LW + sub * 8] = v;
      }
      __syncthreads();
      bf16x8 af0 = *(const bf16x8*)&zs[(wrow + l16) * LZ + k0 + quad * 8];
      bf16x8 af1 = *(const bf16x8*)&zs[(wrow + 16 + l16) * LZ + k0 + quad * 8];
      #pragma unroll
      for (int ct = 0; ct < 7; ++ct) {
        bf16x8 bf = *(const bf16x8*)&wsT[(wcol + ct * 16 + l16) * LW + quad * 8];
        hacc[ct]     = __builtin_amdgcn_mfma_f32_16x16x32_bf16(af0, bf, hacc[ct], 0, 0, 0);
        hacc[7 + ct] = __builtin_amdgcn_mfma_f32_16x16x32_bf16(af1, bf, hacc[7 + ct], 0, 0, 0);
      }
    }

    // ---- epilogue1: a = gelu(h + b1) * w_k -> LDS (A-layout, K-contiguous) ----
    #pragma unroll
    for (int ct = 0; ct < 7; ++ct) {
      int hcol = wcol + ct * 16 + l16;
      float bv = (hcol < H) ? b1[(size_t)e * H + hcol] : 0.f;
      #pragma unroll
      for (int rt = 0; rt < 2; ++rt) {
        f32x4 hv = hacc[rt * 7 + ct];
        #pragma unroll
        for (int r = 0; r < 4; ++r) {
          float g = gelu_tanh(hv[r] + bv) * wkv;
          at[(wrow + rt * 16 + quad * 4 + r) * LZ + hcol] = (__bf16)g;
        }
      }
    }
    // b2 contribution (weighted) straight into mix accumulator
    #pragma unroll
    for (int ct = 0; ct < 7; ++ct) {
      int ncol = wcol + ct * 16 + l16;
      float b2v = (ncol < N) ? b2[(size_t)e * N + ncol] * wkv : 0.f;
      #pragma unroll
      for (int r = 0; r < 4; ++r) { macc[ct][r] += b2v; macc[7 + ct][r] += b2v; }
    }

    // ---- GEMM2: mix += (w_k * a) @ W2^T ----
    const uint4* w2src = (const uint4*)(W2b + (size_t)e * HR * NP);
    #pragma unroll 1
    for (int c = 0; c < 7; ++c) {
      int k0 = c * 32;
      __syncthreads();                       // a written / wsT readers done
      for (int p = t; p < 832; p += 256) {
        int r = p >> 2, sub = p & 3;
        uint4 v = w2src[r * 28 + (k0 >> 3) + sub];
        *(uint4*)&wsT[r * LW + sub * 8] = v;
      }
      __syncthreads();
      bf16x8 af0 = *(const bf16x8*)&at[(wrow + l16) * LZ + k0 + quad * 8];
      bf16x8 af1 = *(const bf16x8*)&at[(wrow + 16 + l16) * LZ + k0 + quad * 8];
      #pragma unroll
      for (int ct = 0; ct < 7; ++ct) {
        bf16x8 bf = *(const bf16x8*)&wsT[(wcol + ct * 16 + l16) * LW + quad * 8];
        macc[ct]     = __builtin_amdgcn_mfma_f32_16x16x32_bf16(af0, bf, macc[ct], 0, 0, 0);
        macc[7 + ct] = __builtin_amdgcn_mfma_f32_16x16x32_bf16(af1, bf, macc[7 + ct], 0, 0, 0);
      }
    }
  }

  // ---- write partial mix: mixp[kh][b][d][n], fp32, exclusive region ----
  float* mp = mixp + (((size_t)kh * B + b) * D + d0) * N;
  #pragma unroll
  for (int ct = 0; ct < 7; ++ct) {
    int ncol = wcol + ct * 16 + l16;
    if (ncol < N) {
      #pragma unroll
      for (int rt = 0; rt < 2; ++rt) {
        #pragma unroll
        for (int r = 0; r < 4; ++r) {
          int dr = wrow + rt * 16 + quad * 4 + r;
          mp[(size_t)dr * N + ncol] = macc[rt * 7 + ct][r];
        }
      }
    }
  }
}

// ---------------------------------------------------------------------------
// Kernel 6: out = (mixp0+mixp1 as (B,N,D) via transpose-stage) @ Wo^T + bo
// M = B*N = 6272, K = D = 768, Nout = D = 768. Block: 64 M-rows x 256 E-cols.
// ---------------------------------------------------------------------------
__global__ __launch_bounds__(256, 2) void k_outproj(
    const float* __restrict__ mixp, const __bf16* __restrict__ Wob,
    const float* __restrict__ bo, float* __restrict__ out) {
  __shared__ __bf16 As[64 * LW];
  __shared__ __bf16 Bs[256 * LW];

  int m0 = (blockIdx.x % 98) * 64;
  int e0 = (blockIdx.x / 98) * 256;
  int t = threadIdx.x;
  int lane = t & 63, wave = t >> 6;
  int quad = lane >> 4, l16 = lane & 15;
  int wrow = (wave & 1) * 32;
  int wcol = (wave >> 1) * 128;

  f32x4 acc[16];
  #pragma unroll
  for (int i = 0; i < 16; ++i) acc[i] = (f32x4){0.f, 0.f, 0.f, 0.f};

  const uint4* wsrc = (const uint4*)Wob;
  #pragma unroll 1
  for (int c = 0; c < 24; ++c) {
    int k0 = c * 32;
    __syncthreads();
    // A tile: sum the two mix halves, cast bf16, store K-contiguous
    #pragma unroll
    for (int i = 0; i < 8; ++i) {
      int idx = t + i * 256;
      int ml = idx & 63, kl = idx >> 6;
      int m = m0 + ml;
      int bb = m / N, n = m % N;
      size_t off = ((size_t)bb * D + k0 + kl) * N + n;
      float v = mixp[off] + mixp[off + (size_t)B * D * N];
      As[ml * LW + kl] = (__bf16)v;
    }
    // B tile: Wo rows e0..e0+255, cols k0..k0+31
    for (int p = t; p < 1024; p += 256) {
      int r = p >> 2, sub = p & 3;
      uint4 v = wsrc[(((size_t)(e0 + r)) * D + k0) / 8 + sub];
      *(uint4*)&Bs[r * LW + sub * 8] = v;
    }
    __syncthreads();
    bf16x8 a0 = *(const bf16x8*)&As[(wrow + l16) * LW + quad * 8];
    bf16x8 a1 = *(const bf16x8*)&As[(wrow + 16 + l16) * LW + quad * 8];
    #pragma unroll
    for (int ct = 0; ct < 8; ++ct) {
      bf16x8 bfr = *(const bf16x8*)&Bs[(wcol + ct * 16 + l16) * LW + quad * 8];
      acc[ct]     = __builtin_amdgcn_mfma_f32_16x16x32_bf16(a0, bfr, acc[ct], 0, 0, 0);
      acc[8 + ct] = __builtin_amdgcn_mfma_f32_16x16x32_bf16(a1, bfr, acc[8 + ct], 0, 0, 0);
    }
  }

  #pragma unroll
  for (int ct = 0; ct < 8; ++ct) {
    int e = e0 + wcol + ct * 16 + l16;
    float bov = bo[e];
    #pragma unroll
    for (int rt = 0; rt < 2; ++rt) {
      #pragma unroll
      for (int r = 0; r < 4; ++r) {
        int m = m0 + wrow + rt * 16 + quad * 4 + r;
        out[(size_t)m * D + e] = acc[rt * 8 + ct][r] + bov;
      }
    }
  }
}

// ---------------------------------------------------------------------------
extern "C" void kernel_launch(void* const* d_in, const int* in_sizes, int n_in,
                              void* d_out, int out_size, void* d_ws, size_t ws_size,
                              hipStream_t stream) {
  const float* x  = (const float*)d_in[0];
  const float* Wr = (const float*)d_in[1];
  const float* W1 = (const float*)d_in[2];
  const float* b1 = (const float*)d_in[3];
  const float* W2 = (const float*)d_in[4];
  const float* b2 = (const float*)d_in[5];
  const float* Wo = (const float*)d_in[6];
  const float* bo = (const float*)d_in[7];
  float* out = (float*)d_out;

  char* p = (char*)d_ws;
  auto alloc = [&](size_t bytes) {
    char* r = p;
    p += (bytes + 255) & ~(size_t)255;
    return r;
  };
  __bf16* zb   = (__bf16*)alloc((size_t)B * D * NP * 2);
  float*  mu   = (float*)alloc((size_t)B * D * 4);
  __bf16* W1b  = (__bf16*)alloc((size_t)E * HR * NP * 2);
  __bf16* W2b  = (__bf16*)alloc((size_t)E * HR * NP * 2);
  __bf16* Wob  = (__bf16*)alloc((size_t)D * D * 2);
  float*  mixp = (float*)alloc((size_t)2 * B * D * N * 4);
  float*  probs= (float*)alloc((size_t)B * E * 4);
  int*    idxg = (int*)alloc((size_t)B * TK * 4);
  float*  wg   = (float*)alloc((size_t)B * TK * 4);

  k_ln<<<dim3((B * D) / 256), dim3(256), 0, stream>>>(x, zb, mu);
  k_convert<<<dim3(75104), dim3(256), 0, stream>>>(W1, W2, Wo, W1b, W2b, Wob);
  k_router<<<dim3(B), dim3(256), 0, stream>>>(mu, Wr, probs, idxg, wg);
  k_aux<<<dim3(1), dim3(256), 0, stream>>>(probs, idxg, out + (size_t)B * N * D);
  k_expert<<<dim3(768), dim3(256), 0, stream>>>(zb, W1b, W2b, b1, b2, idxg, wg, mixp);
  k_outproj<<<dim3(294), dim3(256), 0, stream>>>(mixp, Wob, bo, out);
}

// Round 2
// 737.212 us; speedup vs baseline: 1.1303x; 1.1303x over previous
//
#include <hip/hip_runtime.h>
#include <math.h>

// ---- problem constants ----
constexpr int B  = 32;
constexpr int N  = 196;   // tokens
constexpr int D  = 768;   // channels
constexpr int E  = 200;   // experts
constexpr int TK = 20;    // top-k
constexpr int H  = 196;   // hidden

constexpr int NP = 224;   // padded K-dim (196 -> 7*32)
constexpr int HR = 224;   // padded row count for W1b/W2b (so staging never OOB)
constexpr int LZ = 232;   // LDS stride for z / a tiles (bf16): 116 dwords -> 2-way free
constexpr int LK = 40;    // LDS stride for k_outproj tiles

constexpr int NGRP = 4;   // expert groups (5 experts each) -> grid 1536 = 3 full rounds

typedef __bf16 bf16x8 __attribute__((ext_vector_type(8)));
typedef __bf16 bf16x4 __attribute__((ext_vector_type(4)));
typedef float  f32x4  __attribute__((ext_vector_type(4)));

#define GLDS16(gp, lp)                                                        \
  __builtin_amdgcn_global_load_lds(                                           \
      (const __attribute__((address_space(1))) void*)(gp),                    \
      (__attribute__((address_space(3))) void*)(lp), 16, 0, 0)

// fast tanh-gelu: x * sigmoid(1.595769*(x + 0.044715 x^3)); exp2 form.
__device__ __forceinline__ float gelu_fast(float x) {
  float u = x * fmaf(x * x, 0.044715f, 1.0f);
  float e = exp2f(-2.3022084f * u);   // 1.595769 * log2(e) = 2.3022084
  return x * __builtin_amdgcn_rcpf(1.0f + e);
}

// ---------------------------------------------------------------------------
// Kernel 1: fused token-mean + layernorm-over-N, write z bf16 (B,D,224) padded
// ---------------------------------------------------------------------------
__global__ void k_ln(const float* __restrict__ x, __bf16* __restrict__ zb,
                     float* __restrict__ mu) {
  int t = blockIdx.x * 256 + threadIdx.x;        // [0, B*D)
  if (t >= B * D) return;
  int b = t / D;
  const float* xp = x + (size_t)b * N * D + (t % D);
  float s = 0.f, sq = 0.f;
  #pragma unroll 4
  for (int n = 0; n < N; ++n) {
    float v = xp[(size_t)n * D];
    s += v; sq += v * v;
  }
  float m   = s * (1.0f / N);
  float var = sq * (1.0f / N) - m * m;
  float rs  = rsqrtf(var + 1e-5f);
  mu[t] = m;
  __bf16* zr = zb + (size_t)t * NP;
  #pragma unroll 4
  for (int n = 0; n < N; ++n) {
    float v = xp[(size_t)n * D];
    zr[n] = (__bf16)((v - m) * rs);
  }
  for (int n = N; n < NP; ++n) zr[n] = (__bf16)0.f;
}

// ---------------------------------------------------------------------------
// Kernel 2a: W1,W2 -> zero-padded bf16 (E,224,224). 32-bit math, float4 reads.
// grid (49, E, 2); 196 = 49*4 so quads never straddle the valid edge.
// ---------------------------------------------------------------------------
__global__ void k_convert_w(const float* __restrict__ W1, const float* __restrict__ W2,
                            __bf16* __restrict__ W1b, __bf16* __restrict__ W2b) {
  int t = blockIdx.x * 256 + threadIdx.x;        // [0, 12544)
  int e = blockIdx.y;
  int r = t / 56;                                 // [0, 224)
  int c4 = (t - r * 56) * 4;                      // 0,4,...,220
  const float* src = blockIdx.z == 0 ? W1 : W2;
  __bf16* dst = blockIdx.z == 0 ? W1b : W2b;
  bf16x4 o = {(__bf16)0.f, (__bf16)0.f, (__bf16)0.f, (__bf16)0.f};
  if (r < 196 && c4 < 196) {
    float4 v = *(const float4*)&src[(e * 196 + r) * 196 + c4];
    o[0] = (__bf16)v.x; o[1] = (__bf16)v.y; o[2] = (__bf16)v.z; o[3] = (__bf16)v.w;
  }
  *(bf16x4*)&dst[((size_t)e * HR + r) * NP + c4] = o;
}

// Kernel 2b: Wo -> bf16
__global__ void k_convert_wo(const float* __restrict__ Wo, __bf16* __restrict__ Wob) {
  int t = blockIdx.x * 256 + threadIdx.x;        // [0, 147456)
  float4 v = *(const float4*)&Wo[t * 4];
  bf16x4 o = {(__bf16)v.x, (__bf16)v.y, (__bf16)v.z, (__bf16)v.w};
  *(bf16x4*)&Wob[t * 4] = o;
}

// ---------------------------------------------------------------------------
// Kernel 3: router — logits, softmax, top-20, renormalized weights.
// ---------------------------------------------------------------------------
__global__ void k_router(const float* __restrict__ mu, const float* __restrict__ Wr,
                         float* __restrict__ probs, int* __restrict__ idxg,
                         float* __restrict__ wg) {
  int b = blockIdx.x;
  int t = threadIdx.x;
  __shared__ float sp[E];
  __shared__ float smax, ssum;
  __shared__ float svals[TK];
  __shared__ int   sidx[TK];

  float logit = 0.f;
  if (t < E) {
    const float* m  = mu + (size_t)b * D;
    const float* wr = Wr + (size_t)t * D;
    float acc = 0.f;
    #pragma unroll 4
    for (int d = 0; d < D; ++d) acc = fmaf(m[d], wr[d], acc);
    logit = acc;
    sp[t] = acc;
  }
  __syncthreads();
  if (t == 0) {
    float mx = sp[0];
    for (int e = 1; e < E; ++e) mx = fmaxf(mx, sp[e]);
    smax = mx;
  }
  __syncthreads();
  if (t < E) sp[t] = expf(logit - smax);
  __syncthreads();
  if (t == 0) {
    float s = 0.f;
    for (int e = 0; e < E; ++e) s += sp[e];
    ssum = s;
  }
  __syncthreads();
  if (t < E) {
    sp[t] = sp[t] / ssum;
    probs[(size_t)b * E + t] = sp[t];
  }
  __syncthreads();

  for (int k = 0; k < TK; ++k) {
    if (t < 64) {
      float bv = -1e30f; int bi = 0;
      for (int e = t; e < E; e += 64) {
        float v = sp[e];
        if (v > bv) { bv = v; bi = e; }
      }
      #pragma unroll
      for (int off = 32; off > 0; off >>= 1) {
        float ov = __shfl_down(bv, off);
        int   oi = __shfl_down(bi, off);
        if (ov > bv || (ov == bv && oi < bi)) { bv = ov; bi = oi; }
      }
      if (t == 0) {
        svals[k] = bv; sidx[k] = bi;
        sp[bi] = -2e30f;
      }
    }
    __syncthreads();
  }
  if (t == 0) {
    float s = 0.f;
    for (int k = 0; k < TK; ++k) s += svals[k];
    float inv = 1.0f / s;
    for (int k = 0; k < TK; ++k) {
      wg[b * TK + k]   = svals[k] * inv;
      idxg[b * TK + k] = sidx[k];
    }
  }
}

// ---------------------------------------------------------------------------
// Kernel 4: aux loss -> out[B*N*D]
// ---------------------------------------------------------------------------
__global__ void k_aux(const float* __restrict__ probs, const int* __restrict__ idxg,
                      float* __restrict__ out_aux) {
  __shared__ float cs[E];
  int t = threadIdx.x;
  if (t < E) {
    float s = 0.f;
    for (int b = 0; b < B; ++b) s += probs[(size_t)b * E + t];
    cs[t] = s;
  }
  __syncthreads();
  if (t == 0) {
    float a = 0.f;
    for (int b = 0; b < B; ++b) a += cs[idxg[b * TK]];
    out_aux[0] = a * ((float)E / ((float)B * (float)B));
  }
}

// ---------------------------------------------------------------------------
// Kernel 5: fused expert MLP. Block = (g of 5 experts, d-tile of 64, b).
// W tiles staged with async global_load_lds into [k4][row] 16B-slot layout
// (contiguous in lane order; 2-way-free reads). Grid 1536 = 3 rounds @2/CU.
// ---------------------------------------------------------------------------
__global__ __launch_bounds__(256, 2) void k_expert(
    const __bf16* __restrict__ zb, const __bf16* __restrict__ W1b,
    const __bf16* __restrict__ W2b, const float* __restrict__ b1,
    const float* __restrict__ b2, const int* __restrict__ idxg,
    const float* __restrict__ wg, __bf16* __restrict__ mixp) {
  __shared__ alignas(16) __bf16 zs[64 * LZ];
  __shared__ alignas(16) __bf16 at[64 * LZ];
  __shared__ alignas(16) __bf16 ws[4 * 224 * 8];   // 896 slots x 16B = 14336 B

  int bi = blockIdx.x;
  int g  = bi & 3;
  int dt = (bi >> 2) % 12;
  int b  = bi / 48;
  int d0 = dt * 64;
  int t = threadIdx.x;
  int lane = t & 63, wave = t >> 6;
  int quad = lane >> 4, l16 = lane & 15;
  int wrow = (wave & 1) * 32;
  int wcol = (wave >> 1) * 112;

  // stage z tile (once per block)
  {
    const uint4* src = (const uint4*)(zb + ((size_t)b * D + d0) * NP);
    for (int p = t; p < 1792; p += 256) {
      int row = p / 28, sub = p % 28;
      uint4 v = src[p];
      *(uint4*)&zs[row * LZ + sub * 8] = v;
    }
  }

  // per-lane staging source offsets (bytes, k0=0) + LDS chunk bases
  int nch = (wave < 2) ? 4 : 3;
  int soff[4]; int lbase[4];
  #pragma unroll
  for (int i = 0; i < 4; ++i) {
    int c = wave + i * 4;           // chunk id, < 16 (used only if < 14)
    int slot = c * 64 + lane;
    int k4 = slot / 224;
    int r  = slot - k4 * 224;
    soff[i]  = r * (NP * 2) + k4 * 16;
    lbase[i] = c * 512;             // bf16 elems
  }
  __syncthreads();

  f32x4 macc[14];
  #pragma unroll
  for (int i = 0; i < 14; ++i) macc[i] = (f32x4){0.f, 0.f, 0.f, 0.f};

  #pragma unroll 1
  for (int kk = g * 5; kk < g * 5 + 5; ++kk) {
    int   e   = idxg[b * TK + kk];
    float wkv = wg[b * TK + kk];
    const char* w1p = (const char*)(W1b + (size_t)e * HR * NP);
    const char* w2p = (const char*)(W2b + (size_t)e * HR * NP);

    // ---- GEMM1: h = z @ W1^T ----
    f32x4 hacc[14];
    #pragma unroll
    for (int i = 0; i < 14; ++i) hacc[i] = (f32x4){0.f, 0.f, 0.f, 0.f};

    #pragma unroll 1
    for (int c = 0; c < 7; ++c) {
      int k0 = c * 32;
      __syncthreads();                       // ws readers of previous tile done
      const char* wp = w1p + k0 * 2;
      for (int i = 0; i < nch; ++i) GLDS16(wp + soff[i], &ws[lbase[i]]);
      __syncthreads();                       // drain: loads landed
      bf16x8 af0 = *(const bf16x8*)&zs[(wrow + l16) * LZ + k0 + quad * 8];
      bf16x8 af1 = *(const bf16x8*)&zs[(wrow + 16 + l16) * LZ + k0 + quad * 8];
      #pragma unroll
      for (int ct = 0; ct < 7; ++ct) {
        bf16x8 bf = *(const bf16x8*)&ws[(quad * 224 + wcol + ct * 16 + l16) * 8];
        hacc[ct]     = __builtin_amdgcn_mfma_f32_16x16x32_bf16(af0, bf, hacc[ct], 0, 0, 0);
        hacc[7 + ct] = __builtin_amdgcn_mfma_f32_16x16x32_bf16(af1, bf, hacc[7 + ct], 0, 0, 0);
      }
    }

    // ---- epilogue1: a = gelu(h + b1) * w_k -> at (pad cols forced to 0) ----
    #pragma unroll
    for (int ct = 0; ct < 7; ++ct) {
      int hcol = wcol + ct * 16 + l16;
      bool valid = hcol < H;
      float bv = valid ? b1[e * H + hcol] : 0.f;
      #pragma unroll
      for (int rt = 0; rt < 2; ++rt) {
        f32x4 hv = hacc[rt * 7 + ct];
        #pragma unroll
        for (int r = 0; r < 4; ++r) {
          float gv = valid ? gelu_fast(hv[r] + bv) * wkv : 0.f;
          at[(wrow + rt * 16 + quad * 4 + r) * LZ + hcol] = (__bf16)gv;
        }
      }
    }
    // b2 contribution (weighted) straight into mix accumulator
    #pragma unroll
    for (int ct = 0; ct < 7; ++ct) {
      int ncol = wcol + ct * 16 + l16;
      float b2v = (ncol < N) ? b2[e * N + ncol] * wkv : 0.f;
      #pragma unroll
      for (int r = 0; r < 4; ++r) { macc[ct][r] += b2v; macc[7 + ct][r] += b2v; }
    }

    // ---- GEMM2: mix += a @ W2^T ----
    #pragma unroll 1
    for (int c = 0; c < 7; ++c) {
      int k0 = c * 32;
      __syncthreads();                       // at written / prior ws readers done
      const char* wp = w2p + k0 * 2;
      for (int i = 0; i < nch; ++i) GLDS16(wp + soff[i], &ws[lbase[i]]);
      __syncthreads();
      bf16x8 af0 = *(const bf16x8*)&at[(wrow + l16) * LZ + k0 + quad * 8];
      bf16x8 af1 = *(const bf16x8*)&at[(wrow + 16 + l16) * LZ + k0 + quad * 8];
      #pragma unroll
      for (int ct = 0; ct < 7; ++ct) {
        bf16x8 bf = *(const bf16x8*)&ws[(quad * 224 + wcol + ct * 16 + l16) * 8];
        macc[ct]     = __builtin_amdgcn_mfma_f32_16x16x32_bf16(af0, bf, macc[ct], 0, 0, 0);
        macc[7 + ct] = __builtin_amdgcn_mfma_f32_16x16x32_bf16(af1, bf, macc[7 + ct], 0, 0, 0);
      }
    }
  }

  // ---- write partial mix (bf16): mixp[g][b][d][n] ----
  __bf16* mp = mixp + (((size_t)g * B + b) * D + d0) * N;
  #pragma unroll
  for (int ct = 0; ct < 7; ++ct) {
    int ncol = wcol + ct * 16 + l16;
    if (ncol < N) {
      #pragma unroll
      for (int rt = 0; rt < 2; ++rt) {
        #pragma unroll
        for (int r = 0; r < 4; ++r) {
          int dr = wrow + rt * 16 + quad * 4 + r;
          mp[(size_t)dr * N + ncol] = (__bf16)macc[rt * 7 + ct][r];
        }
      }
    }
  }
}

// ---------------------------------------------------------------------------
// Kernel 6: out = (sum_g mixp_g, as (B,N,D)) @ Wo^T + bo
// ---------------------------------------------------------------------------
__global__ __launch_bounds__(256, 2) void k_outproj(
    const __bf16* __restrict__ mixp, const __bf16* __restrict__ Wob,
    const float* __restrict__ bo, float* __restrict__ out) {
  __shared__ __bf16 As[64 * LK];
  __shared__ __bf16 Bs[256 * LK];
  const size_t GS = (size_t)B * D * N;

  int m0 = (blockIdx.x % 98) * 64;
  int e0 = (blockIdx.x / 98) * 256;
  int t = threadIdx.x;
  int lane = t & 63, wave = t >> 6;
  int quad = lane >> 4, l16 = lane & 15;
  int wrow = (wave & 1) * 32;
  int wcol = (wave >> 1) * 128;

  f32x4 acc[16];
  #pragma unroll
  for (int i = 0; i < 16; ++i) acc[i] = (f32x4){0.f, 0.f, 0.f, 0.f};

  const uint4* wsrc = (const uint4*)Wob;
  #pragma unroll 1
  for (int c = 0; c < 24; ++c) {
    int k0 = c * 32;
    __syncthreads();
    #pragma unroll
    for (int i = 0; i < 8; ++i) {
      int idx = t + i * 256;
      int ml = idx & 63, kl = idx >> 6;
      int m = m0 + ml;
      int bb = m / N, n = m % N;
      size_t off = ((size_t)bb * D + k0 + kl) * N + n;
      float v = (float)mixp[off] + (float)mixp[off + GS] +
                (float)mixp[off + 2 * GS] + (float)mixp[off + 3 * GS];
      As[ml * LK + kl] = (__bf16)v;
    }
    for (int p = t; p < 1024; p += 256) {
      int r = p >> 2, sub = p & 3;
      uint4 v = wsrc[(((size_t)(e0 + r)) * D + k0) / 8 + sub];
      *(uint4*)&Bs[r * LK + sub * 8] = v;
    }
    __syncthreads();
    bf16x8 a0 = *(const bf16x8*)&As[(wrow + l16) * LK + quad * 8];
    bf16x8 a1 = *(const bf16x8*)&As[(wrow + 16 + l16) * LK + quad * 8];
    #pragma unroll
    for (int ct = 0; ct < 8; ++ct) {
      bf16x8 bfr = *(const bf16x8*)&Bs[(wcol + ct * 16 + l16) * LK + quad * 8];
      acc[ct]     = __builtin_amdgcn_mfma_f32_16x16x32_bf16(a0, bfr, acc[ct], 0, 0, 0);
      acc[8 + ct] = __builtin_amdgcn_mfma_f32_16x16x32_bf16(a1, bfr, acc[8 + ct], 0, 0, 0);
    }
  }

  #pragma unroll
  for (int ct = 0; ct < 8; ++ct) {
    int e = e0 + wcol + ct * 16 + l16;
    float bov = bo[e];
    #pragma unroll
    for (int rt = 0; rt < 2; ++rt) {
      #pragma unroll
      for (int r = 0; r < 4; ++r) {
        int m = m0 + wrow + rt * 16 + quad * 4 + r;
        out[(size_t)m * D + e] = acc[rt * 8 + ct][r] + bov;
      }
    }
  }
}

// ---------------------------------------------------------------------------
extern "C" void kernel_launch(void* const* d_in, const int* in_sizes, int n_in,
                              void* d_out, int out_size, void* d_ws, size_t ws_size,
                              hipStream_t stream) {
  const float* x  = (const float*)d_in[0];
  const float* Wr = (const float*)d_in[1];
  const float* W1 = (const float*)d_in[2];
  const float* b1 = (const float*)d_in[3];
  const float* W2 = (const float*)d_in[4];
  const float* b2 = (const float*)d_in[5];
  const float* Wo = (const float*)d_in[6];
  const float* bo = (const float*)d_in[7];
  float* out = (float*)d_out;

  char* p = (char*)d_ws;
  auto alloc = [&](size_t bytes) {
    char* r = p;
    p += (bytes + 255) & ~(size_t)255;
    return r;
  };
  __bf16* zb   = (__bf16*)alloc((size_t)B * D * NP * 2);
  float*  mu   = (float*)alloc((size_t)B * D * 4);
  __bf16* W1b  = (__bf16*)alloc((size_t)E * HR * NP * 2);
  __bf16* W2b  = (__bf16*)alloc((size_t)E * HR * NP * 2);
  __bf16* Wob  = (__bf16*)alloc((size_t)D * D * 2);
  __bf16* mixp = (__bf16*)alloc((size_t)NGRP * B * D * N * 2);
  float*  probs= (float*)alloc((size_t)B * E * 4);
  int*    idxg = (int*)alloc((size_t)B * TK * 4);
  float*  wg   = (float*)alloc((size_t)B * TK * 4);

  k_ln<<<dim3((B * D) / 256), dim3(256), 0, stream>>>(x, zb, mu);
  k_convert_w<<<dim3(49, E, 2), dim3(256), 0, stream>>>(W1, W2, W1b, W2b);
  k_convert_wo<<<dim3(576), dim3(256), 0, stream>>>(Wo, Wob);
  k_router<<<dim3(B), dim3(256), 0, stream>>>(mu, Wr, probs, idxg, wg);
  k_aux<<<dim3(1), dim3(256), 0, stream>>>(probs, idxg, out + (size_t)B * N * D);
  k_expert<<<dim3(32 * 12 * NGRP), dim3(256), 0, stream>>>(zb, W1b, W2b, b1, b2,
                                                           idxg, wg, mixp);
  k_outproj<<<dim3(294), dim3(256), 0, stream>>>(mixp, Wob, bo, out);
}